// Round 7
// baseline (66.220 us; speedup 1.0000x reference)
//
#include <hip/hip_runtime.h>

#define NBINS  256               // uniform bins in x-space over [-6, 6]
#define NCLS   20
#define CDIM   21
#define HW     (512 * 512)
#define NPIX   (8 * HW)
#define NCHUNK 2048
#define CHUNK  (NPIX / NCHUNK)   // 1024 pixels/block; divides HW
#define NCOPY  32                // global histogram replicas (merge contention /32)
#define XSCALE 21.3333333f       // 256/12
#define XBIAS  128.0f            // 6 * XSCALE

__device__ __forceinline__ float4 gld_f4(const float* p) {
    float4 r;
    asm volatile("global_load_dwordx4 %0, %1, off" : "=v"(r) : "v"(p));
    return r;
}
__device__ __forceinline__ int4 gld_i4(const int* p) {
    int4 r;
    asm volatile("global_load_dwordx4 %0, %1, off" : "=v"(r) : "v"(p));
    return r;
}

__global__ __launch_bounds__(256) void zero_ws(unsigned* __restrict__ w, int n) {
    int i = blockIdx.x * 256 + threadIdx.x;
    if (i < n) w[i] = 0u;
}

// One block = one 1024-pixel chunk, all 20 classes. Bins are monotone in x
// (no sigmoid here!); positives bin at t=-x, which mirrors the symmetric grid.
__global__ __launch_bounds__(256, 4) void lovasz_hist(const float* __restrict__ pred,
                                                      const int* __restrict__ label,
                                                      unsigned long long* __restrict__ g_hist) {
    __shared__ unsigned s_hist[NCLS * NBINS];   // 20 KB
    const int tid = threadIdx.x;

    const long base = (long)blockIdx.x * CHUNK;
    const int  b    = (int)(base / HW);
    const long hw0  = base - (long)b * HW;

    // Issue ALL loads first (asm-pinned): label int4 + 20 pred float4.
    const int4 l = gld_i4(label + base + tid * 4);
    const float* pbase = pred + ((long)b * CDIM + 1) * HW + hw0 + tid * 4;
    float4 x[NCLS];
#pragma unroll
    for (int c = 0; c < NCLS; ++c)
        x[c] = gld_f4(pbase + (long)c * HW);

    // Zero LDS while the 21 loads are in flight.
    for (int i = tid; i < NCLS * NBINS; i += 256) s_hist[i] = 0u;
    __syncthreads();

    asm volatile("s_waitcnt vmcnt(0)" ::: "memory");
    __builtin_amdgcn_sched_barrier(0);

#pragma unroll
    for (int j = 0; j < 4; ++j) {
        const int lv = (j == 0) ? l.x : (j == 1) ? l.y : (j == 2) ? l.z : l.w;
#pragma unroll
        for (int c = 0; c < NCLS; ++c) {
            const float xv  = (j == 0) ? x[c].x : (j == 1) ? x[c].y : (j == 2) ? x[c].z : x[c].w;
            const bool  pos = (lv == c + 1);
            const float t   = pos ? -xv : xv;          // error = sigmoid(t), monotone in t
            int bin = (int)(t * XSCALE + XBIAS);       // x-space bin; no exp/rcp
            bin = bin < 0 ? 0 : (bin > NBINS - 1 ? NBINS - 1 : bin);
            atomicAdd(&s_hist[c * NBINS + bin], pos ? 0x10001u : 1u);
        }
    }
    __syncthreads();

    // Merge into one of NCOPY global replicas -> contention /NCOPY.
    unsigned long long* gh = g_hist + (size_t)(blockIdx.x & (NCOPY - 1)) * (NCLS * NBINS);
    for (int i = tid; i < NCLS * NBINS; i += 256) {
        const unsigned v = s_hist[i];
        if (v) {
            const unsigned long long pk =
                (unsigned long long)(v & 0xFFFFu) | ((unsigned long long)(v >> 16) << 32);
            atomicAdd(&gh[i], pk);
        }
    }
}

// Per-class: sum replicas, descending scan over 256 x-bins, Lovasz-grad sum.
// Error midpoint of bin b is sigmoid(xmid(b)) — computed here, 256 exps total.
__global__ __launch_bounds__(NBINS) void lovasz_scan(const unsigned long long* __restrict__ g_hist,
                                                     float* __restrict__ out_pc) {
    const int cls = blockIdx.x;
    const int tid = threadIdx.x;
    const int bin = NBINS - 1 - tid;              // descending error order
    unsigned lc = 0, lp = 0;
#pragma unroll 4
    for (int r = 0; r < NCOPY; ++r) {
        const unsigned long long v = g_hist[(size_t)r * (NCLS * NBINS) + cls * NBINS + bin];
        lc += (unsigned)(v & 0xFFFFFFFFull);
        lp += (unsigned)(v >> 32);
    }

    __shared__ unsigned sc[NBINS], sp[NBINS];
    sc[tid] = lc;
    sp[tid] = lp;
    __syncthreads();

    unsigned exc_c = 0, exc_p = 0, G = 0;
    for (int i = 0; i < NBINS; ++i) {             // tiny kernel; naive scan fine
        if (i < tid) { exc_c += sc[i]; exc_p += sp[i]; }
        G += sp[i];
    }

    float contrib = 0.0f;
    if (G > 0 && lc > 0) {
        const float fG = (float)G;
        // J(i,m) = 1 - (G-m)/(G+i-m); exact in f32 (counts < 2^23)
        const float Jprev = 1.0f - (fG - (float)exc_p) / (fG + (float)(exc_c - exc_p));
        const unsigned ic = exc_c + lc, mp = exc_p + lp;
        const float Jcur  = 1.0f - (fG - (float)mp) / (fG + (float)(ic - mp));
        const float xmid  = ((float)bin + 0.5f) * (12.0f / (float)NBINS) - 6.0f;
        const float emid  = 1.0f / (1.0f + __expf(-xmid));   // error midpoint
        contrib = emid * (Jcur - Jprev);
    }

    __shared__ float sf[NBINS];
    sf[tid] = contrib;
    __syncthreads();
    for (int s = NBINS / 2; s > 0; s >>= 1) {
        if (tid < s) sf[tid] += sf[tid + s];
        __syncthreads();
    }
    if (tid == 0) {
        out_pc[cls * 2]     = sf[0];
        out_pc[cls * 2 + 1] = (G > 0) ? 1.0f : 0.0f;
    }
}

__global__ void lovasz_final(const float* __restrict__ out_pc, float* __restrict__ out) {
    if (threadIdx.x == 0 && blockIdx.x == 0) {
        float s = 0.0f, n = 0.0f;
        for (int c = 0; c < NCLS; ++c) {
            s += out_pc[c * 2];
            n += out_pc[c * 2 + 1];
        }
        out[0] = s / n;
    }
}

extern "C" void kernel_launch(void* const* d_in, const int* in_sizes, int n_in,
                              void* d_out, int out_size, void* d_ws, size_t ws_size,
                              hipStream_t stream) {
    const float* pred  = (const float*)d_in[0];
    const int*   label = (const int*)d_in[1];

    unsigned long long* g_hist = (unsigned long long*)d_ws;
    float* out_pc = (float*)(g_hist + (size_t)NCOPY * NCLS * NBINS);
    float* out    = (float*)d_out;

    const int nzero = NCOPY * NCLS * NBINS * 2;  // u64 hist as u32 words
    zero_ws<<<(nzero + 255) / 256, 256, 0, stream>>>((unsigned*)g_hist, nzero);
    lovasz_hist<<<NCHUNK, 256, 0, stream>>>(pred, label, g_hist);
    lovasz_scan<<<NCLS, NBINS, 0, stream>>>(g_hist, out_pc);
    lovasz_final<<<1, 64, 0, stream>>>(out_pc, out);
}

// Round 8
// 50.864 us; speedup vs baseline: 1.3019x; 1.3019x over previous
//
#include <hip/hip_runtime.h>

#define NBINS  128               // uniform bins in x-space over [-6, 6]
#define NCLS   20
#define CDIM   21
#define HW     (512 * 512)
#define NPIX   (8 * HW)
#define NCHUNK 2048
#define CHUNK  (NPIX / NCHUNK)   // 1024 pixels/block; divides HW
#define NCOPY  32                // global histogram replicas (merge contention /32)
#define XSCALE 10.6666667f       // 128/12
#define XBIAS  64.0f             // 6 * XSCALE

__device__ __forceinline__ float4 gld_f4(const float* p) {
    float4 r;
    asm volatile("global_load_dwordx4 %0, %1, off" : "=v"(r) : "v"(p));
    return r;
}
__device__ __forceinline__ int4 gld_i4(const int* p) {
    int4 r;
    asm volatile("global_load_dwordx4 %0, %1, off" : "=v"(r) : "v"(p));
    return r;
}

__global__ __launch_bounds__(256) void zero_ws(unsigned* __restrict__ w, int n) {
    int i = blockIdx.x * 256 + threadIdx.x;
    if (i < n) w[i] = 0u;
}

// One block = one 1024-pixel chunk, all 20 classes, binned in x-space
// (monotone in sigmoid; positives bin at -x on the symmetric grid).
// Channel loads are software-pipelined in 4 groups of 5 with counted vmcnt:
// compute of group g overlaps the in-flight loads of groups g+1 / g+2.
__global__ __launch_bounds__(256, 4) void lovasz_hist(const float* __restrict__ pred,
                                                      const int* __restrict__ label,
                                                      unsigned long long* __restrict__ g_hist) {
    __shared__ unsigned s_hist[NCLS * NBINS];   // 10 KB
    const int tid = threadIdx.x;

    const long base = (long)blockIdx.x * CHUNK;
    const int  b    = (int)(base / HW);
    const long hw0  = base - (long)b * HW;
    const float* pbase = pred + ((long)b * CDIM + 1) * HW + hw0 + tid * 4;

    // --- issue G0 (label + ch0..4) and G1 (ch5..9): 11 outstanding ---
    const int4 l = gld_i4(label + base + tid * 4);
    float4 xa[5], xb[5];
#pragma unroll
    for (int k = 0; k < 5; ++k) xa[k] = gld_f4(pbase + (long)k * HW);
#pragma unroll
    for (int k = 0; k < 5; ++k) xb[k] = gld_f4(pbase + (long)(5 + k) * HW);

    // zero LDS + barrier under the load latency (barrier only waits lgkmcnt:
    // the asm loads are invisible to the compiler's waitcnt insertion)
    for (int i = tid; i < NCLS * NBINS; i += 256) s_hist[i] = 0u;
    __syncthreads();

    // per-group compute: classes cbase..cbase+4 from x[5]
    auto compute5 = [&](const float4* x, int cbase) {
#pragma unroll
        for (int j = 0; j < 4; ++j) {
            const int lv = (j == 0) ? l.x : (j == 1) ? l.y : (j == 2) ? l.z : l.w;
#pragma unroll
            for (int k = 0; k < 5; ++k) {
                const float xv = (j == 0) ? x[k].x : (j == 1) ? x[k].y
                               : (j == 2) ? x[k].z : x[k].w;
                const bool  pos = (lv == cbase + k + 1);
                const float t   = pos ? -xv : xv;     // error = sigmoid(t)
                int bin = (int)__builtin_fmaf(t, XSCALE, XBIAS);
                bin = bin < 0 ? 0 : (bin > NBINS - 1 ? NBINS - 1 : bin);
                atomicAdd(&s_hist[(cbase + k) * NBINS + bin], pos ? 0x10001u : 1u);
            }
        }
    };

    asm volatile("s_waitcnt vmcnt(5)" ::: "memory");   // G0 landed, G1 in flight
    __builtin_amdgcn_sched_barrier(0);
    float4 xc[5];
#pragma unroll
    for (int k = 0; k < 5; ++k) xc[k] = gld_f4(pbase + (long)(10 + k) * HW);  // G2
    compute5(xa, 0);

    asm volatile("s_waitcnt vmcnt(5)" ::: "memory");   // G1 landed, G2 in flight
    __builtin_amdgcn_sched_barrier(0);
    float4 xd[5];
#pragma unroll
    for (int k = 0; k < 5; ++k) xd[k] = gld_f4(pbase + (long)(15 + k) * HW);  // G3
    compute5(xb, 5);

    asm volatile("s_waitcnt vmcnt(5)" ::: "memory");   // G2 landed, G3 in flight
    __builtin_amdgcn_sched_barrier(0);
    compute5(xc, 10);

    asm volatile("s_waitcnt vmcnt(0)" ::: "memory");   // G3 landed
    __builtin_amdgcn_sched_barrier(0);
    compute5(xd, 15);

    __syncthreads();

    // Merge into one of NCOPY global replicas -> contention /NCOPY.
    unsigned long long* gh = g_hist + (size_t)(blockIdx.x & (NCOPY - 1)) * (NCLS * NBINS);
    for (int i = tid; i < NCLS * NBINS; i += 256) {
        const unsigned v = s_hist[i];
        if (v) {
            const unsigned long long pk =
                (unsigned long long)(v & 0xFFFFu) | ((unsigned long long)(v >> 16) << 32);
            atomicAdd(&gh[i], pk);
        }
    }
}

// Per-class: sum replicas, descending scan over 128 x-bins, Lovasz-grad sum.
// Error midpoint of bin b is sigmoid(xmid(b)) — 128 exps total, free.
__global__ __launch_bounds__(NBINS) void lovasz_scan(const unsigned long long* __restrict__ g_hist,
                                                     float* __restrict__ out_pc) {
    const int cls = blockIdx.x;
    const int tid = threadIdx.x;
    const int bin = NBINS - 1 - tid;              // descending error order
    unsigned lc = 0, lp = 0;
#pragma unroll 4
    for (int r = 0; r < NCOPY; ++r) {
        const unsigned long long v = g_hist[(size_t)r * (NCLS * NBINS) + cls * NBINS + bin];
        lc += (unsigned)(v & 0xFFFFFFFFull);
        lp += (unsigned)(v >> 32);
    }

    __shared__ unsigned sc[NBINS], sp[NBINS];
    sc[tid] = lc;
    sp[tid] = lp;
    __syncthreads();

    unsigned exc_c = 0, exc_p = 0, G = 0;
    for (int i = 0; i < NBINS; ++i) {             // tiny kernel; naive scan fine
        if (i < tid) { exc_c += sc[i]; exc_p += sp[i]; }
        G += sp[i];
    }

    float contrib = 0.0f;
    if (G > 0 && lc > 0) {
        const float fG = (float)G;
        // J(i,m) = 1 - (G-m)/(G+i-m); exact in f32 (counts < 2^23)
        const float Jprev = 1.0f - (fG - (float)exc_p) / (fG + (float)(exc_c - exc_p));
        const unsigned ic = exc_c + lc, mp = exc_p + lp;
        const float Jcur  = 1.0f - (fG - (float)mp) / (fG + (float)(ic - mp));
        const float xmid  = ((float)bin + 0.5f) * (12.0f / (float)NBINS) - 6.0f;
        const float emid  = 1.0f / (1.0f + __expf(-xmid));   // error midpoint
        contrib = emid * (Jcur - Jprev);
    }

    __shared__ float sf[NBINS];
    sf[tid] = contrib;
    __syncthreads();
    for (int s = NBINS / 2; s > 0; s >>= 1) {
        if (tid < s) sf[tid] += sf[tid + s];
        __syncthreads();
    }
    if (tid == 0) {
        out_pc[cls * 2]     = sf[0];
        out_pc[cls * 2 + 1] = (G > 0) ? 1.0f : 0.0f;
    }
}

__global__ void lovasz_final(const float* __restrict__ out_pc, float* __restrict__ out) {
    if (threadIdx.x == 0 && blockIdx.x == 0) {
        float s = 0.0f, n = 0.0f;
        for (int c = 0; c < NCLS; ++c) {
            s += out_pc[c * 2];
            n += out_pc[c * 2 + 1];
        }
        out[0] = s / n;
    }
}

extern "C" void kernel_launch(void* const* d_in, const int* in_sizes, int n_in,
                              void* d_out, int out_size, void* d_ws, size_t ws_size,
                              hipStream_t stream) {
    const float* pred  = (const float*)d_in[0];
    const int*   label = (const int*)d_in[1];

    unsigned long long* g_hist = (unsigned long long*)d_ws;
    float* out_pc = (float*)(g_hist + (size_t)NCOPY * NCLS * NBINS);
    float* out    = (float*)d_out;

    const int nzero = NCOPY * NCLS * NBINS * 2;  // u64 hist as u32 words
    zero_ws<<<(nzero + 255) / 256, 256, 0, stream>>>((unsigned*)g_hist, nzero);
    lovasz_hist<<<NCHUNK, 256, 0, stream>>>(pred, label, g_hist);
    lovasz_scan<<<NCLS, NBINS, 0, stream>>>(g_hist, out_pc);
    lovasz_final<<<1, 64, 0, stream>>>(out_pc, out);
}

// Round 9
// 45.635 us; speedup vs baseline: 1.4511x; 1.1146x over previous
//
#include <hip/hip_runtime.h>

#define NBINS  128               // uniform bins in x-space over [-6, 6]
#define NCLS   20
#define CDIM   21
#define HW     (512 * 512)
#define NPIX   (8 * HW)
#define NCHUNK 1024
#define CHUNK  (NPIX / NCHUNK)   // 2048 pixels/block (2 tiles of 1024); divides HW
#define NCOPY  16                // global histogram replicas
#define XSCALE 10.6666667f       // 128/12
#define XBIAS  64.0f             // 6 * XSCALE

__device__ __forceinline__ float4 gld_f4(const float* p) {
    float4 r;
    asm volatile("global_load_dwordx4 %0, %1, off" : "=v"(r) : "v"(p));
    return r;
}
__device__ __forceinline__ int4 gld_i4(const int* p) {
    int4 r;
    asm volatile("global_load_dwordx4 %0, %1, off" : "=v"(r) : "v"(p));
    return r;
}

__global__ __launch_bounds__(256) void zero_ws(unsigned* __restrict__ w, int n) {
    int i = blockIdx.x * 256 + threadIdx.x;
    if (i < n) w[i] = 0u;
}

// One block = 2048 pixels (two 1024-pixel tiles), all 20 classes, binned in
// x-space (monotone in sigmoid; positives bin at -x on the symmetric grid).
// The two tiles chain into one 8-phase counted-vmcnt pipeline: loads of the
// next group/tile stay in flight under compute; vmcnt(0) only at the very end.
__global__ __launch_bounds__(256, 4) void lovasz_hist(const float* __restrict__ pred,
                                                      const int* __restrict__ label,
                                                      unsigned long long* __restrict__ g_hist) {
    __shared__ unsigned s_hist[NCLS * NBINS];   // 10 KB
    const int tid = threadIdx.x;

    const long base = (long)blockIdx.x * CHUNK;
    const int  b    = (int)(base / HW);
    const long hw0  = base - (long)b * HW;
    const float* p0 = pred + ((long)b * CDIM + 1) * HW + hw0 + tid * 4;
    const float* p1 = p0 + 1024;
    const int*   q0 = label + base + tid * 4;
    const int*   q1 = q0 + 1024;

    // --- T0: label + G0 + G1 issued (11 outstanding) ---
    const int4 l0 = gld_i4(q0);
    float4 xa[5], xb[5];
#pragma unroll
    for (int k = 0; k < 5; ++k) xa[k] = gld_f4(p0 + (long)k * HW);
#pragma unroll
    for (int k = 0; k < 5; ++k) xb[k] = gld_f4(p0 + (long)(5 + k) * HW);

    // zero LDS + barrier under the load latency
    for (int i = tid; i < NCLS * NBINS; i += 256) s_hist[i] = 0u;
    __syncthreads();

    auto compute5 = [&](const float4* x, int cbase, const int4& l) {
#pragma unroll
        for (int j = 0; j < 4; ++j) {
            const int lv = (j == 0) ? l.x : (j == 1) ? l.y : (j == 2) ? l.z : l.w;
#pragma unroll
            for (int k = 0; k < 5; ++k) {
                const float xv = (j == 0) ? x[k].x : (j == 1) ? x[k].y
                               : (j == 2) ? x[k].z : x[k].w;
                const bool  pos = (lv == cbase + k + 1);
                const float t   = pos ? -xv : xv;     // error = sigmoid(t)
                int bin = (int)__builtin_fmaf(t, XSCALE, XBIAS);
                bin = bin < 0 ? 0 : (bin > NBINS - 1 ? NBINS - 1 : bin);
                atomicAdd(&s_hist[(cbase + k) * NBINS + bin], pos ? 0x10001u : 1u);
            }
        }
    };

    asm volatile("s_waitcnt vmcnt(5)" ::: "memory");   // T0.G0 ready; G1 in flight
    __builtin_amdgcn_sched_barrier(0);
    float4 xc[5];
#pragma unroll
    for (int k = 0; k < 5; ++k) xc[k] = gld_f4(p0 + (long)(10 + k) * HW);
    compute5(xa, 0, l0);

    asm volatile("s_waitcnt vmcnt(5)" ::: "memory");   // T0.G1 ready
    __builtin_amdgcn_sched_barrier(0);
    float4 xd[5];
#pragma unroll
    for (int k = 0; k < 5; ++k) xd[k] = gld_f4(p0 + (long)(15 + k) * HW);
    compute5(xb, 5, l0);

    asm volatile("s_waitcnt vmcnt(5)" ::: "memory");   // T0.G2 ready
    __builtin_amdgcn_sched_barrier(0);
    const int4 l1 = gld_i4(q1);                        // T1: label + G0 (6 issued)
    float4 ya[5];
#pragma unroll
    for (int k = 0; k < 5; ++k) ya[k] = gld_f4(p1 + (long)k * HW);
    compute5(xc, 10, l0);

    asm volatile("s_waitcnt vmcnt(6)" ::: "memory");   // T0.G3 ready; l1+T1.G0 in flight
    __builtin_amdgcn_sched_barrier(0);
    float4 yb[5];
#pragma unroll
    for (int k = 0; k < 5; ++k) yb[k] = gld_f4(p1 + (long)(5 + k) * HW);
    compute5(xd, 15, l0);

    asm volatile("s_waitcnt vmcnt(5)" ::: "memory");   // l1 + T1.G0 ready
    __builtin_amdgcn_sched_barrier(0);
    float4 yc[5];
#pragma unroll
    for (int k = 0; k < 5; ++k) yc[k] = gld_f4(p1 + (long)(10 + k) * HW);
    compute5(ya, 0, l1);

    asm volatile("s_waitcnt vmcnt(5)" ::: "memory");   // T1.G1 ready
    __builtin_amdgcn_sched_barrier(0);
    float4 yd[5];
#pragma unroll
    for (int k = 0; k < 5; ++k) yd[k] = gld_f4(p1 + (long)(15 + k) * HW);
    compute5(yb, 5, l1);

    asm volatile("s_waitcnt vmcnt(5)" ::: "memory");   // T1.G2 ready
    __builtin_amdgcn_sched_barrier(0);
    compute5(yc, 10, l1);

    asm volatile("s_waitcnt vmcnt(0)" ::: "memory");   // T1.G3 ready (only drain)
    __builtin_amdgcn_sched_barrier(0);
    compute5(yd, 15, l1);

    __syncthreads();

    // Merge into one of NCOPY global replicas.
    unsigned long long* gh = g_hist + (size_t)(blockIdx.x & (NCOPY - 1)) * (NCLS * NBINS);
    for (int i = tid; i < NCLS * NBINS; i += 256) {
        const unsigned v = s_hist[i];
        if (v) {
            const unsigned long long pk =
                (unsigned long long)(v & 0xFFFFu) | ((unsigned long long)(v >> 16) << 32);
            atomicAdd(&gh[i], pk);
        }
    }
}

// Per-class: sum replicas, descending scan over 128 x-bins, Lovasz-grad sum.
// Error midpoint of bin b is sigmoid(xmid(b)) — 128 exps total, free.
__global__ __launch_bounds__(NBINS) void lovasz_scan(const unsigned long long* __restrict__ g_hist,
                                                     float* __restrict__ out_pc) {
    const int cls = blockIdx.x;
    const int tid = threadIdx.x;
    const int bin = NBINS - 1 - tid;              // descending error order
    unsigned lc = 0, lp = 0;
#pragma unroll 4
    for (int r = 0; r < NCOPY; ++r) {
        const unsigned long long v = g_hist[(size_t)r * (NCLS * NBINS) + cls * NBINS + bin];
        lc += (unsigned)(v & 0xFFFFFFFFull);
        lp += (unsigned)(v >> 32);
    }

    __shared__ unsigned sc[NBINS], sp[NBINS];
    sc[tid] = lc;
    sp[tid] = lp;
    __syncthreads();

    unsigned exc_c = 0, exc_p = 0, G = 0;
    for (int i = 0; i < NBINS; ++i) {             // tiny kernel; naive scan fine
        if (i < tid) { exc_c += sc[i]; exc_p += sp[i]; }
        G += sp[i];
    }

    float contrib = 0.0f;
    if (G > 0 && lc > 0) {
        const float fG = (float)G;
        // J(i,m) = 1 - (G-m)/(G+i-m); exact in f32 (counts < 2^23)
        const float Jprev = 1.0f - (fG - (float)exc_p) / (fG + (float)(exc_c - exc_p));
        const unsigned ic = exc_c + lc, mp = exc_p + lp;
        const float Jcur  = 1.0f - (fG - (float)mp) / (fG + (float)(ic - mp));
        const float xmid  = ((float)bin + 0.5f) * (12.0f / (float)NBINS) - 6.0f;
        const float emid  = 1.0f / (1.0f + __expf(-xmid));   // error midpoint
        contrib = emid * (Jcur - Jprev);
    }

    __shared__ float sf[NBINS];
    sf[tid] = contrib;
    __syncthreads();
    for (int s = NBINS / 2; s > 0; s >>= 1) {
        if (tid < s) sf[tid] += sf[tid + s];
        __syncthreads();
    }
    if (tid == 0) {
        out_pc[cls * 2]     = sf[0];
        out_pc[cls * 2 + 1] = (G > 0) ? 1.0f : 0.0f;
    }
}

__global__ void lovasz_final(const float* __restrict__ out_pc, float* __restrict__ out) {
    if (threadIdx.x == 0 && blockIdx.x == 0) {
        float s = 0.0f, n = 0.0f;
        for (int c = 0; c < NCLS; ++c) {
            s += out_pc[c * 2];
            n += out_pc[c * 2 + 1];
        }
        out[0] = s / n;
    }
}

extern "C" void kernel_launch(void* const* d_in, const int* in_sizes, int n_in,
                              void* d_out, int out_size, void* d_ws, size_t ws_size,
                              hipStream_t stream) {
    const float* pred  = (const float*)d_in[0];
    const int*   label = (const int*)d_in[1];

    unsigned long long* g_hist = (unsigned long long*)d_ws;
    float* out_pc = (float*)(g_hist + (size_t)NCOPY * NCLS * NBINS);
    float* out    = (float*)d_out;

    const int nzero = NCOPY * NCLS * NBINS * 2;  // u64 hist as u32 words
    zero_ws<<<(nzero + 255) / 256, 256, 0, stream>>>((unsigned*)g_hist, nzero);
    lovasz_hist<<<NCHUNK, 256, 0, stream>>>(pred, label, g_hist);
    lovasz_scan<<<NCLS, NBINS, 0, stream>>>(g_hist, out_pc);
    lovasz_final<<<1, 64, 0, stream>>>(out_pc, out);
}

// Round 11
// 41.176 us; speedup vs baseline: 1.6082x; 1.1083x over previous
//
#include <hip/hip_runtime.h>

#define NBINS  128               // uniform bins in x-space over [-6, 6]
#define NCLS   20
#define CDIM   21
#define HW     (512 * 512)
#define NPIX   (8 * HW)
#define NCHUNK 512
#define CHUNK  (NPIX / NCHUNK)   // 4096 pixels/block = 4 tiles of 1024; divides HW
#define NCOPY  8                 // global histogram replicas
#define XSCALE 10.6666667f       // 128/12
#define XBIAS  64.0f             // 6 * XSCALE

__device__ __forceinline__ float4 gld_f4(const float* p) {
    float4 r;
    asm volatile("global_load_dwordx4 %0, %1, off" : "=v"(r) : "v"(p));
    return r;
}
__device__ __forceinline__ int4 gld_i4(const int* p) {
    int4 r;
    asm volatile("global_load_dwordx4 %0, %1, off" : "=v"(r) : "v"(p));
    return r;
}

__global__ __launch_bounds__(256) void zero_ws(unsigned* __restrict__ w, int n) {
    int i = blockIdx.x * 256 + threadIdx.x;
    if (i < n) w[i] = 0u;
}

// One block = 4096 pixels (4 tiles of 1024), all 20 classes, binned in x-space
// (monotone in sigmoid; positives bin at -x on the symmetric grid).
// 16-phase counted-vmcnt pipeline over groups g=0..15 (tile g/4, channels
// (g%4)*5..+4). Steady state: groups g+1, g+2 in flight -> vmcnt(10).
// Labels for all 4 tiles load up front. Single vmcnt(0) at the last phase.
__global__ __launch_bounds__(256, 4) void lovasz_hist(const float* __restrict__ pred,
                                                      const int* __restrict__ label,
                                                      unsigned long long* __restrict__ g_hist) {
    __shared__ unsigned s_hist[NCLS * NBINS];   // 10 KB
    const int tid = threadIdx.x;

    const long base = (long)blockIdx.x * CHUNK;
    const int  b    = (int)(base / HW);
    const long hw0  = base - (long)b * HW;
    const float* pbase = pred + ((long)b * CDIM + 1) * HW + hw0 + tid * 4;
    const int*   q     = label + base + tid * 4;

    // Issue: 4 labels + G0 + G1 (14 outstanding).
    int4 l[4];
#pragma unroll
    for (int t = 0; t < 4; ++t) l[t] = gld_i4(q + t * 1024);
    float4 buf[3][5];
#pragma unroll
    for (int k = 0; k < 5; ++k) buf[0][k] = gld_f4(pbase + (long)k * HW);
#pragma unroll
    for (int k = 0; k < 5; ++k) buf[1][k] = gld_f4(pbase + (long)(5 + k) * HW);

    // zero LDS + barrier under the load latency
    for (int i = tid; i < NCLS * NBINS; i += 256) s_hist[i] = 0u;
    __syncthreads();

    auto compute5 = [&](const float4* x, int cbase, const int4& lab) {
#pragma unroll
        for (int j = 0; j < 4; ++j) {
            const int lv = (j == 0) ? lab.x : (j == 1) ? lab.y : (j == 2) ? lab.z : lab.w;
#pragma unroll
            for (int k = 0; k < 5; ++k) {
                const float xv = (j == 0) ? x[k].x : (j == 1) ? x[k].y
                               : (j == 2) ? x[k].z : x[k].w;
                const bool  pos = (lv == cbase + k + 1);
                const float t   = pos ? -xv : xv;     // error = sigmoid(t)
                const float bf  = fminf(fmaxf(__builtin_fmaf(t, XSCALE, XBIAS), 0.0f), 127.0f);
                const int   bin = (int)bf;
                atomicAdd(&s_hist[(cbase + k) * NBINS + bin], pos ? 0x10001u : 1u);
            }
        }
    };

#pragma unroll
    for (int g = 0; g < 16; ++g) {
        if (g + 2 < 16) {       // issue group g+2 into buf[(g+2)%3]
            const int gg = g + 2;
#pragma unroll
            for (int k = 0; k < 5; ++k)
                buf[gg % 3][k] =
                    gld_f4(pbase + (long)((gg & 3) * 5 + k) * HW + (gg >> 2) * 1024);
        }
        if (g < 14)       asm volatile("s_waitcnt vmcnt(10)" ::: "memory");
        else if (g == 14) asm volatile("s_waitcnt vmcnt(5)" ::: "memory");
        else              asm volatile("s_waitcnt vmcnt(0)" ::: "memory");
        __builtin_amdgcn_sched_barrier(0);
        compute5(buf[g % 3], (g & 3) * 5, l[g >> 2]);
    }

    __syncthreads();

    // Merge into one of NCOPY global replicas.
    unsigned long long* gh = g_hist + (size_t)(blockIdx.x & (NCOPY - 1)) * (NCLS * NBINS);
    for (int i = tid; i < NCLS * NBINS; i += 256) {
        const unsigned v = s_hist[i];
        if (v) {
            const unsigned long long pk =
                (unsigned long long)(v & 0xFFFFu) | ((unsigned long long)(v >> 16) << 32);
            atomicAdd(&gh[i], pk);
        }
    }
}

// Fused scan+final: one wave per class (2 bins/lane), shfl butterfly prefix
// scan in descending-error order, Lovasz-grad weighted sum, block reduce.
__global__ __launch_bounds__(1024) void lovasz_scan(const unsigned long long* __restrict__ g_hist,
                                                    float* __restrict__ out) {
    __shared__ float cls_sum[NCLS];
    __shared__ float cls_cnt[NCLS];
    const int wid  = threadIdx.x >> 6;
    const int lane = threadIdx.x & 63;

#pragma unroll
    for (int it = 0; it < 2; ++it) {
        const int cls = it * 16 + wid;
        if (cls < NCLS) {
            // lane covers descending positions d0=2*lane (bin 127-2l) and d1=d0+1 (bin 126-2l)
            const int bin_lo = 126 - 2 * lane;
            int vc0 = 0, vp0 = 0, vc1 = 0, vp1 = 0;
#pragma unroll
            for (int r = 0; r < NCOPY; ++r) {
                const ulonglong2 v = *reinterpret_cast<const ulonglong2*>(
                    g_hist + ((size_t)r * NCLS + cls) * NBINS + bin_lo);
                vc1 += (int)(v.x & 0xFFFFFFFFull); vp1 += (int)(v.x >> 32);  // bin_lo   -> d1
                vc0 += (int)(v.y & 0xFFFFFFFFull); vp0 += (int)(v.y >> 32);  // bin_lo+1 -> d0
            }
            const int sc = vc0 + vc1, sp = vp0 + vp1;
            int ic = sc, ip = sp;                 // inclusive wave scan over lanes
#pragma unroll
            for (int d = 1; d < 64; d <<= 1) {
                const int tc = __shfl_up(ic, d, 64);
                const int tp = __shfl_up(ip, d, 64);
                if (lane >= d) { ic += tc; ip += tp; }
            }
            const int G   = __shfl(ip, 63, 64);         // total POSITIVES (the R10 bug: was ic)
            const int ec0 = ic - sc, ep0 = ip - sp;     // exclusive prefix at d0
            float contrib = 0.0f;
            if (G > 0) {
                const float fG = (float)G;
                auto J = [&](int i, int m) {
                    return 1.0f - (fG - (float)m) / (fG + (float)(i - m));
                };
                auto EMID = [&](int bn) {
                    const float xm = ((float)bn + 0.5f) * (12.0f / (float)NBINS) - 6.0f;
                    return 1.0f / (1.0f + __expf(-xm));
                };
                if (vc0) {
                    contrib += EMID(127 - 2 * lane) *
                               (J(ec0 + vc0, ep0 + vp0) - J(ec0, ep0));
                }
                if (vc1) {
                    const int ec = ec0 + vc0, ep = ep0 + vp0;
                    contrib += EMID(126 - 2 * lane) *
                               (J(ec + vc1, ep + vp1) - J(ec, ep));
                }
            }
#pragma unroll
            for (int d = 32; d > 0; d >>= 1) contrib += __shfl_down(contrib, d, 64);
            if (lane == 0) {
                cls_sum[cls] = contrib;
                cls_cnt[cls] = (G > 0) ? 1.0f : 0.0f;
            }
        }
    }
    __syncthreads();
    if (threadIdx.x == 0) {
        float s = 0.0f, n = 0.0f;
        for (int c = 0; c < NCLS; ++c) { s += cls_sum[c]; n += cls_cnt[c]; }
        out[0] = s / n;
    }
}

extern "C" void kernel_launch(void* const* d_in, const int* in_sizes, int n_in,
                              void* d_out, int out_size, void* d_ws, size_t ws_size,
                              hipStream_t stream) {
    const float* pred  = (const float*)d_in[0];
    const int*   label = (const int*)d_in[1];

    unsigned long long* g_hist = (unsigned long long*)d_ws;
    float* out = (float*)d_out;

    const int nzero = NCOPY * NCLS * NBINS * 2;  // u64 hist as u32 words
    zero_ws<<<(nzero + 255) / 256, 256, 0, stream>>>((unsigned*)g_hist, nzero);
    lovasz_hist<<<NCHUNK, 256, 0, stream>>>(pred, label, g_hist);
    lovasz_scan<<<1, 1024, 0, stream>>>(g_hist, out);
}